// Round 13
// baseline (315.348 us; speedup 1.0000x reference)
//
#include <hip/hip_runtime.h>
#include <stdint.h>

// Problem constants
#define D_DIM 512
#define K_CB  4096
#define N_TOK 16384
#define TOPK  8

#define TOKB  32    // tokens per vq_main block
#define TOKE  16    // tokens per vq_epi block
#define NPASS 16
#define NSEL  16

typedef __attribute__((ext_vector_type(4)))  int       i32x4;
typedef __attribute__((ext_vector_type(8)))  int       i32x8;
typedef __attribute__((ext_vector_type(16))) float     f32x16;
typedef __attribute__((ext_vector_type(4)))  float     f32x4;
typedef __attribute__((ext_vector_type(4)))  _Float16  f16x4;
typedef __attribute__((ext_vector_type(8)))  _Float16  f16x8;

// branchless top-N insert: N x (v_max_u32 + v_min_u32)
template<int N>
__device__ __forceinline__ void inskey(unsigned int k, unsigned int (&ts)[N]) {
    #pragma unroll
    for (int q = 0; q < N; ++q) {
        unsigned int hi = ts[q] > k ? ts[q] : k;
        unsigned int lo = ts[q] > k ? k : ts[q];
        ts[q] = hi; k = lo;
    }
}

__device__ __forceinline__ f32x16 mfma_step(i32x4 al, i32x4 ah, i32x4 bl, i32x4 bh,
                                            f32x16 acc) {
    return __builtin_amdgcn_mfma_scale_f32_32x32x64_f8f6f4(
        __builtin_shufflevector(al, ah, 0,1,2,3,4,5,6,7),
        __builtin_shufflevector(bl, bh, 0,1,2,3,4,5,6,7),
        acc, 0, 0, 0, 0x7F7F7F7F, 0, 0x7F7F7F7F);
}

// cbf8 = fp8(e4m3) of 64*codebook in 32x32x64-MFMA-A-fragment order (16B-chunk-split);
// cbh  = fp16 row-major codebook (4 MB = one XCD L2; vq_epi gathers it exclusively).
__global__ __launch_bounds__(256) void conv_cb_kernel(
    const float* __restrict__ cb, unsigned char* __restrict__ cbf8,
    _Float16* __restrict__ cbh, float* __restrict__ cnorm,
    float* __restrict__ loss, unsigned int* __restrict__ ticket) {
    const int t = threadIdx.x, gb = blockIdx.x;      // gb: 16-row block 0..255
    if (gb == 0 && t == 0) { *loss = 0.f; *ticket = 0u; }
    const int r16 = t >> 4, c = t & 15;              // row 0..15, 32-k chunk 0..15
    const int row = gb * 16 + r16;
    const float* src = cb + (size_t)row * D_DIM + c * 32;
    _Float16* hrow = cbh + (size_t)row * D_DIM + c * 32;
    float sq = 0.f;
    unsigned int d[8];
    #pragma unroll
    for (int i = 0; i < 8; ++i) {
        float4 v = ((const float4*)src)[i];
        sq += v.x*v.x + v.y*v.y + v.z*v.z + v.w*v.w;
        int dd = __builtin_amdgcn_cvt_pk_fp8_f32(64.f * v.x, 64.f * v.y, 0, false);
        dd     = __builtin_amdgcn_cvt_pk_fp8_f32(64.f * v.z, 64.f * v.w, dd, true);
        d[i] = (unsigned int)dd;
        f16x4 hv = {(_Float16)v.x, (_Float16)v.y, (_Float16)v.z, (_Float16)v.w};
        *(f16x4*)(hrow + i * 4) = hv;
    }
    sq += __shfl_down(sq, 8, 16);
    sq += __shfl_down(sq, 4, 16);
    sq += __shfl_down(sq, 2, 16);
    sq += __shfl_down(sq, 1, 16);
    if (c == 0) cnorm[row] = sq;                     // raw ||c||^2
    const int g = row >> 5, row32 = row & 31;
    const int s = c >> 1, khalf = c & 1;
    unsigned char* base = cbf8 + (size_t)g * 16384 + (size_t)s * 2048
                        + (size_t)(khalf * 32 + row32) * 16;
    i32x4 lo = {(int)d[0], (int)d[1], (int)d[2], (int)d[3]};   // j 0..15
    i32x4 hi = {(int)d[4], (int)d[5], (int)d[6], (int)d[7]};   // j 16..31
    *(i32x4*)(base)        = lo;
    *(i32x4*)(base + 1024) = hi;
}

// Kernel A: staging + fp8 MFMA distance passes + biased-key top-16 selection + merge.
// r12 post-mortem: VALU 46% / MFMA 17% / FETCH 25 MB -> dependency-latency-bound at
// 2 blocks/CU. This rev: ncn joins the {xs8|keys} union (LDS 57.8K -> 41K), B read
// from LDS every pass (r10: identical to B-in-reg), launch_bounds(512,6) caps VGPR
// at ~85 -> 3 blocks/CU, 6 waves/EU; setprio removed (suspected selection starver).
__global__ __launch_bounds__(512, 6) void vq_main(
    const float* __restrict__ x, const unsigned char* __restrict__ cbf8,
    const float* __restrict__ cnorm, int* __restrict__ tki_g)
{
    __shared__ union {
        struct {
            unsigned char xs8[TOKB * D_DIM];         // 16384 B: fp8(16x), B-frag order
            float ncn[K_CB];                         // 16384 B: 32768 - 512*||c||^2
        } s;                                         // live: staging + passes
        unsigned int keys[256 * 32];                 // 32768 B: [list*8+e][token]; merge
    } u;
    __shared__ unsigned int pk[TOKB * 65];           // 8320 B: stage-1 partials (padded)

    const int t    = threadIdx.x;
    const int lane = t & 63;
    const int w    = t >> 6;          // wave 0..7
    const int m32  = lane & 31;
    const int half = lane >> 5;
    const int tok0 = blockIdx.x * TOKB;

    const char* cb8l = (const char*)cbf8 + (size_t)lane * 16;

    // ---- stage xs8 in B-fragment order (fp8 of 16*x), 16B-chunk-split ----
    {
        const int token = t >> 4, c = t & 15;        // 16 threads/token
        const int s2 = c >> 1, lh = c & 1;
        const f32x4* src = (const f32x4*)(x + (size_t)(tok0 + token) * D_DIM + c * 32);
        unsigned int d[8];
        #pragma unroll
        for (int i = 0; i < 8; ++i) {
            f32x4 v = src[i];
            int dd = __builtin_amdgcn_cvt_pk_fp8_f32(16.f * v.x, 16.f * v.y, 0, false);
            dd     = __builtin_amdgcn_cvt_pk_fp8_f32(16.f * v.z, 16.f * v.w, dd, true);
            d[i] = (unsigned int)dd;
        }
        unsigned char* base = u.s.xs8 + s2 * 2048 + (lh * 32 + token) * 16;
        i32x4 lo = {(int)d[0], (int)d[1], (int)d[2], (int)d[3]};   // j 0..15
        i32x4 hi = {(int)d[4], (int)d[5], (int)d[6], (int)d[7]};   // j 16..31
        *(i32x4*)(base)        = lo;
        *(i32x4*)(base + 1024) = hi;
    }
    {   // ncn = 32768 - 512*||c||^2 => key = 512*(2xc - ||c||^2) + 32768 > 0
        float4 v0 = ((const float4*)cnorm)[t];
        float4 v1 = ((const float4*)cnorm)[t + 512];
        float4 n0 = {32768.f - 512.f * v0.x, 32768.f - 512.f * v0.y,
                     32768.f - 512.f * v0.z, 32768.f - 512.f * v0.w};
        float4 n1 = {32768.f - 512.f * v1.x, 32768.f - 512.f * v1.y,
                     32768.f - 512.f * v1.z, 32768.f - 512.f * v1.w};
        *(float4*)&u.s.ncn[t * 4]         = n0;
        *(float4*)&u.s.ncn[(t + 512) * 4] = n1;
    }
    __syncthreads();

    unsigned int tsA[8], tsB[8];      // per-lane lists: even passes / odd passes
    #pragma unroll
    for (int i = 0; i < 8; ++i) { tsA[i] = 0u; tsB[i] = 0u; }

    const unsigned char* pb = u.s.xs8 + lane * 16;

    for (int pp = 0; pp < NPASS; ++pp) {
        const int p  = (pp + 2 * w) & 15;            // stagger waves across passes
        const int ga = p * 8 + w;                    // centroid 32-group 0..127
        f32x16 acc;
        #pragma unroll
        for (int g = 0; g < 4; ++g) {                // acc init (LDS bcast)
            float4 n0 = *(const float4*)&u.s.ncn[ga * 32 + g * 8 + 4 * half];
            acc[g*4+0]=n0.x; acc[g*4+1]=n0.y; acc[g*4+2]=n0.z; acc[g*4+3]=n0.w;
        }
        const char* ab = cb8l + (size_t)ga * 16384;
        #pragma unroll
        for (int s = 0; s < 8; ++s) {                // A from global (L2), B from LDS
            i32x4 al = *(const i32x4*)(ab + s * 2048);
            i32x4 ah = *(const i32x4*)(ab + s * 2048 + 1024);
            i32x4 bl = *(const i32x4*)(pb + s * 2048);
            i32x4 bh = *(const i32x4*)(pb + s * 2048 + 1024);
            acc = mfma_step(al, ah, bl, bh, acc);
        }
        // biased keys: scores ~[27e3,38e3] > 0 => uint-ordered; low 12 bits = 4095-idx
        const unsigned int K0 = 4095u - (unsigned int)(ga * 32) - 4u * (unsigned int)half;
        if ((pp & 1) == 0) {
            #pragma unroll
            for (int r = 0; r < 16; ++r) {
                const unsigned int cr = (unsigned int)((r & 3) + 8 * (r >> 2));
                inskey((__float_as_uint(acc[r]) & 0xFFFFF000u) | (K0 - cr), tsA);
            }
        } else {
            #pragma unroll
            for (int r = 0; r < 16; ++r) {
                const unsigned int cr = (unsigned int)((r & 3) + 8 * (r >> 2));
                inskey((__float_as_uint(acc[r]) & 0xFFFFF000u) | (K0 - cr), tsB);
            }
        }
    }

    // ---- merge ----
    __syncthreads();   // xs8 + ncn dead -> keys
    {
        const int L0 = w * 4 + half * 2;             // lists L0 (even), L0+1 (odd)
        #pragma unroll
        for (int e = 0; e < 8; ++e) {
            u.keys[(L0 * 8 + e) * 32 + m32]       = tsA[e];
            u.keys[((L0 + 1) * 8 + e) * 32 + m32] = tsB[e];
        }
    }
    __syncthreads();
    if (t < 128) {     // stage 1: 4 threads/token, 64 keys (8 lists) -> top-16 partials
        const int token = t >> 2, sub = t & 3;
        unsigned int bs[16];
        #pragma unroll
        for (int i = 0; i < 16; ++i) bs[i] = 0u;
        #pragma unroll 2
        for (int k = 0; k < 64; ++k) inskey(u.keys[(sub * 64 + k) * 32 + token], bs);
        #pragma unroll
        for (int e = 0; e < 16; ++e) pk[token * 65 + sub * 16 + e] = bs[e];
    }
    __syncthreads();
    if (t < TOKB) {    // stage 2: top-16 fp8 candidates -> global tki
        unsigned int bs[NSEL];
        #pragma unroll
        for (int i = 0; i < NSEL; ++i) bs[i] = 0u;
        #pragma unroll 2
        for (int k = 0; k < 64; ++k) inskey(pk[t * 65 + k], bs);
        #pragma unroll
        for (int r = 0; r < NSEL; ++r)
            tki_g[(size_t)blockIdx.x * (TOKB * NSEL) + t * NSEL + r] =
                4095 - (int)(bs[r] & 0xFFFu);
    }
}

// Kernel B: fp16-codebook rescore (fp32 accum) of the 16 candidates, top-8, softmax,
// fp16 decode, loss. cbh (4 MB) is the ONLY gathered table -> L2-resident.
// 256 threads / 16 tokens -> 1024 blocks for gather-latency hiding.
__global__ __launch_bounds__(256) void vq_epi(
    const float* __restrict__ x, const _Float16* __restrict__ cbh,
    const float* __restrict__ cnorm, const int* __restrict__ tki_g,
    float* __restrict__ out, float* __restrict__ loss_acc,
    unsigned int* __restrict__ ticket)
{
    __shared__ int   tkl[TOKE * NSEL];               // 256 ints
    __shared__ float tks[TOKE * 17];
    __shared__ float tkw[TOKE * TOPK];
    __shared__ int   tkif[TOKE * TOPK];
    __shared__ float redbuf[4];

    const int t    = threadIdx.x;
    const int lane = t & 63;
    const int w    = t >> 6;
    const int tok0 = blockIdx.x * TOKE;

    tkl[t] = tki_g[(size_t)blockIdx.x * (TOKE * NSEL) + t];   // 256 = 16*16 exactly
    __syncthreads();

    {   // fp16 rescore of 16 candidates: 16 threads/token, x row read ONCE,
        // thread sl owns 8-dim granules {sl+16i, i<4}: 256 B contiguous per row/quarter
        const int token = t >> 4, sl = t & 15;
        const f32x4* xr = (const f32x4*)(x + (size_t)(tok0 + token) * D_DIM);
        f32x4 xv[8];
        #pragma unroll
        for (int i = 0; i < 4; ++i) {
            xv[2*i]   = xr[(sl + 16*i) * 2];
            xv[2*i+1] = xr[(sl + 16*i) * 2 + 1];
        }
        #pragma unroll
        for (int hh = 0; hh < 2; ++hh) {
            float pd[8];
            #pragma unroll
            for (int e = 0; e < 8; ++e) {
                const int idx = tkl[token * NSEL + hh * 8 + e];
                const f16x8* cr = (const f16x8*)(cbh + (size_t)idx * D_DIM);
                float dot = 0.f;
                #pragma unroll
                for (int i = 0; i < 4; ++i) {
                    f16x8 cv = cr[sl + 16*i];
                    dot += xv[2*i].x   * (float)cv[0] + xv[2*i].y   * (float)cv[1]
                         + xv[2*i].z   * (float)cv[2] + xv[2*i].w   * (float)cv[3]
                         + xv[2*i+1].x * (float)cv[4] + xv[2*i+1].y * (float)cv[5]
                         + xv[2*i+1].z * (float)cv[6] + xv[2*i+1].w * (float)cv[7];
                }
                pd[e] = dot;
            }
            #pragma unroll
            for (int e = 0; e < 8; ++e) {
                pd[e] += __shfl_down(pd[e], 8, 16);
                pd[e] += __shfl_down(pd[e], 4, 16);
                pd[e] += __shfl_down(pd[e], 2, 16);
                pd[e] += __shfl_down(pd[e], 1, 16);
            }
            if (sl == 0) {
                #pragma unroll
                for (int e = 0; e < 8; ++e)
                    tks[token * 17 + hh * 8 + e] =
                        2.f * pd[e] - cnorm[tkl[token * NSEL + hh * 8 + e]];
            }
        }
    }
    __syncthreads();
    if (t < TOKE) {    // top-8 of the 16, softmax
        unsigned int bs[8];
        #pragma unroll
        for (int i = 0; i < 8; ++i) bs[i] = 0u;
        #pragma unroll
        for (int e = 0; e < NSEL; ++e) {
            unsigned int uu = __float_as_uint(tks[t * 17 + e]);
            uu ^= (unsigned int)((int)uu >> 31) | 0x80000000u;   // monotone float->uint
            inskey((uu & 0xFFFFFFF0u) | (unsigned int)e, bs);
        }
        const float m = tks[t * 17 + (int)(bs[0] & 15u)];
        float wv[TOPK], sum = 0.f;
        int ids[TOPK];
        #pragma unroll
        for (int r = 0; r < TOPK; ++r) {
            const int e = (int)(bs[r] & 15u);
            wv[r] = __expf(tks[t * 17 + e] - m); sum += wv[r];
            ids[r] = tkl[t * NSEL + e];
        }
        const float inv = 1.f / sum;
        #pragma unroll
        for (int r = 0; r < TOPK; ++r) {
            tkw[t * TOPK + r] = wv[r] * inv;
            tkif[t * TOPK + r] = ids[r];
        }
    }
    __syncthreads();
    // output + loss partial: fp16 decode, dense 16 B/lane float4 stores (r10 pattern)
    float lsum = 0.f;
    #pragma unroll 1
    for (int it = 0; it < (TOKE * (D_DIM / 4)) / 256; ++it) {    // 8 iters
        const int p = it * 256 + t;
        const int token = p >> 7, d4 = p & 127;
        float4 q = {0.f, 0.f, 0.f, 0.f};
        #pragma unroll
        for (int e = 0; e < TOPK; ++e) {
            const float wv = tkw[token * TOPK + e];
            const int  idx = tkif[token * TOPK + e];
            f16x4 cv = *(const f16x4*)(cbh + (size_t)idx * D_DIM + d4 * 4);
            q.x += wv * (float)cv[0]; q.y += wv * (float)cv[1];
            q.z += wv * (float)cv[2]; q.w += wv * (float)cv[3];
        }
        const size_t go = (size_t)(tok0 + token) * (D_DIM / 4) + d4;
        f32x4 xv = __builtin_nontemporal_load((const f32x4*)x + go);
        const float ex = q.x - xv.x, ey = q.y - xv.y, ez = q.z - xv.z, ew = q.w - xv.w;
        lsum += ex*ex + ey*ey + ez*ez + ew*ew;
        f32x4 qv = {q.x, q.y, q.z, q.w};
        __builtin_nontemporal_store(qv, (f32x4*)out + go);
    }
    #pragma unroll
    for (int off = 32; off > 0; off >>= 1) lsum += __shfl_down(lsum, off, 64);
    if (lane == 0) redbuf[w] = lsum;
    __syncthreads();
    if (t == 0) {
        float s = 0.f;
        #pragma unroll
        for (int i = 0; i < 4; ++i) s += redbuf[i];
        atomicAdd(loss_acc, s);
        __threadfence();
        unsigned int prev = atomicAdd(ticket, 1u);
        if (prev == (unsigned int)(gridDim.x - 1)) {   // last block finalizes loss
            __threadfence();
            float total = atomicAdd(loss_acc, 0.f);    // coherent read
            out[(size_t)N_TOK * D_DIM] = 1.25f * total / (float)((size_t)N_TOK * D_DIM);
        }
    }
}

extern "C" void kernel_launch(void* const* d_in, const int* in_sizes, int n_in,
                              void* d_out, int out_size, void* d_ws, size_t ws_size,
                              hipStream_t stream) {
    const float* x  = (const float*)d_in[0];   // [8,2048,512] fp32
    const float* cb = (const float*)d_in[1];   // [4096,512] fp32
    float* out = (float*)d_out;

    char* ws = (char*)d_ws;
    unsigned char* cbf8   = (unsigned char*)ws;              // 2 MB, fp8 fragment-ordered
    _Float16*      cbh    = (_Float16*)(ws + 2097152);       // 4 MB, fp16 row-major
    float*         cnorm  = (float*)(ws + 6291456);          // 16 KB
    float*         loss   = (float*)(ws + 6307840);          // 4 B
    unsigned int*  ticket = (unsigned int*)(ws + 6307904);   // 4 B
    int*           tki_g  = (int*)(ws + 6308096);            // 1 MB top-16 indices

    conv_cb_kernel<<<256, 256, 0, stream>>>(cb, cbf8, cbh, cnorm, loss, ticket);
    vq_main<<<N_TOK / TOKB, 512, 0, stream>>>(x, cbf8, cnorm, tki_g);
    vq_epi<<<N_TOK / TOKE, 256, 0, stream>>>(x, cbh, cnorm, tki_g, out, loss, ticket);
}

// Round 14
// 222.738 us; speedup vs baseline: 1.4158x; 1.4158x over previous
//
#include <hip/hip_runtime.h>
#include <stdint.h>

// Problem constants
#define D_DIM 512
#define K_CB  4096
#define N_TOK 16384
#define TOPK  8

#define TOKB  32    // tokens per vq_main block
#define TOKE  16    // tokens per vq_epi block
#define NPASS 16
#define NSEL  16

typedef __attribute__((ext_vector_type(4)))  int       i32x4;
typedef __attribute__((ext_vector_type(8)))  int       i32x8;
typedef __attribute__((ext_vector_type(16))) float     f32x16;
typedef __attribute__((ext_vector_type(4)))  float     f32x4;
typedef __attribute__((ext_vector_type(4)))  _Float16  f16x4;
typedef __attribute__((ext_vector_type(8)))  _Float16  f16x8;

// branchless top-N insert: N x (v_max_u32 + v_min_u32)
template<int N>
__device__ __forceinline__ void inskey(unsigned int k, unsigned int (&ts)[N]) {
    #pragma unroll
    for (int q = 0; q < N; ++q) {
        unsigned int hi = ts[q] > k ? ts[q] : k;
        unsigned int lo = ts[q] > k ? k : ts[q];
        ts[q] = hi; k = lo;
    }
}

__device__ __forceinline__ f32x16 mfma_step(i32x4 al, i32x4 ah, i32x4 bl, i32x4 bh,
                                            f32x16 acc) {
    return __builtin_amdgcn_mfma_scale_f32_32x32x64_f8f6f4(
        __builtin_shufflevector(al, ah, 0,1,2,3,4,5,6,7),
        __builtin_shufflevector(bl, bh, 0,1,2,3,4,5,6,7),
        acc, 0, 0, 0, 0x7F7F7F7F, 0, 0x7F7F7F7F);
}

// cbf8 = fp8(e4m3) of 64*codebook in 32x32x64-MFMA-A-fragment order (16B-chunk-split);
// cbh  = fp16 row-major codebook (4 MB = one XCD L2; vq_epi gathers it exclusively).
__global__ __launch_bounds__(256) void conv_cb_kernel(
    const float* __restrict__ cb, unsigned char* __restrict__ cbf8,
    _Float16* __restrict__ cbh, float* __restrict__ cnorm,
    float* __restrict__ loss, unsigned int* __restrict__ ticket) {
    const int t = threadIdx.x, gb = blockIdx.x;      // gb: 16-row block 0..255
    if (gb == 0 && t == 0) { *loss = 0.f; *ticket = 0u; }
    const int r16 = t >> 4, c = t & 15;              // row 0..15, 32-k chunk 0..15
    const int row = gb * 16 + r16;
    const float* src = cb + (size_t)row * D_DIM + c * 32;
    _Float16* hrow = cbh + (size_t)row * D_DIM + c * 32;
    float sq = 0.f;
    unsigned int d[8];
    #pragma unroll
    for (int i = 0; i < 8; ++i) {
        float4 v = ((const float4*)src)[i];
        sq += v.x*v.x + v.y*v.y + v.z*v.z + v.w*v.w;
        int dd = __builtin_amdgcn_cvt_pk_fp8_f32(64.f * v.x, 64.f * v.y, 0, false);
        dd     = __builtin_amdgcn_cvt_pk_fp8_f32(64.f * v.z, 64.f * v.w, dd, true);
        d[i] = (unsigned int)dd;
        f16x4 hv = {(_Float16)v.x, (_Float16)v.y, (_Float16)v.z, (_Float16)v.w};
        *(f16x4*)(hrow + i * 4) = hv;
    }
    sq += __shfl_down(sq, 8, 16);
    sq += __shfl_down(sq, 4, 16);
    sq += __shfl_down(sq, 2, 16);
    sq += __shfl_down(sq, 1, 16);
    if (c == 0) cnorm[row] = sq;                     // raw ||c||^2
    const int g = row >> 5, row32 = row & 31;
    const int s = c >> 1, khalf = c & 1;
    unsigned char* base = cbf8 + (size_t)g * 16384 + (size_t)s * 2048
                        + (size_t)(khalf * 32 + row32) * 16;
    i32x4 lo = {(int)d[0], (int)d[1], (int)d[2], (int)d[3]};   // j 0..15
    i32x4 hi = {(int)d[4], (int)d[5], (int)d[6], (int)d[7]};   // j 16..31
    *(i32x4*)(base)        = lo;
    *(i32x4*)(base + 1024) = hi;
}

// Kernel A: staging + fp8 MFMA distance passes + biased-key top-16 selection + merge.
// r13 post-mortem: launch_bounds(512,6) made the allocator emit 40 VGPR + spill
// (FETCH 25->416 MB). This rev: identical to r13 EXCEPT launch_bounds(512,4) --
// natural 64-VGPR allocation; the 41.4 KB LDS footprint alone gives 3 blocks/CU
// (24 waves, 6/EU) with no register cap.
__global__ __launch_bounds__(512, 4) void vq_main(
    const float* __restrict__ x, const unsigned char* __restrict__ cbf8,
    const float* __restrict__ cnorm, int* __restrict__ tki_g)
{
    __shared__ union {
        struct {
            unsigned char xs8[TOKB * D_DIM];         // 16384 B: fp8(16x), B-frag order
            float ncn[K_CB];                         // 16384 B: 32768 - 512*||c||^2
        } s;                                         // live: staging + passes
        unsigned int keys[256 * 32];                 // 32768 B: [list*8+e][token]; merge
    } u;
    __shared__ unsigned int pk[TOKB * 65];           // 8320 B: stage-1 partials (padded)

    const int t    = threadIdx.x;
    const int lane = t & 63;
    const int w    = t >> 6;          // wave 0..7
    const int m32  = lane & 31;
    const int half = lane >> 5;
    const int tok0 = blockIdx.x * TOKB;

    const char* cb8l = (const char*)cbf8 + (size_t)lane * 16;

    // ---- stage xs8 in B-fragment order (fp8 of 16*x), 16B-chunk-split ----
    {
        const int token = t >> 4, c = t & 15;        // 16 threads/token
        const int s2 = c >> 1, lh = c & 1;
        const f32x4* src = (const f32x4*)(x + (size_t)(tok0 + token) * D_DIM + c * 32);
        unsigned int d[8];
        #pragma unroll
        for (int i = 0; i < 8; ++i) {
            f32x4 v = src[i];
            int dd = __builtin_amdgcn_cvt_pk_fp8_f32(16.f * v.x, 16.f * v.y, 0, false);
            dd     = __builtin_amdgcn_cvt_pk_fp8_f32(16.f * v.z, 16.f * v.w, dd, true);
            d[i] = (unsigned int)dd;
        }
        unsigned char* base = u.s.xs8 + s2 * 2048 + (lh * 32 + token) * 16;
        i32x4 lo = {(int)d[0], (int)d[1], (int)d[2], (int)d[3]};   // j 0..15
        i32x4 hi = {(int)d[4], (int)d[5], (int)d[6], (int)d[7]};   // j 16..31
        *(i32x4*)(base)        = lo;
        *(i32x4*)(base + 1024) = hi;
    }
    {   // ncn = 32768 - 512*||c||^2 => key = 512*(2xc - ||c||^2) + 32768 > 0
        float4 v0 = ((const float4*)cnorm)[t];
        float4 v1 = ((const float4*)cnorm)[t + 512];
        float4 n0 = {32768.f - 512.f * v0.x, 32768.f - 512.f * v0.y,
                     32768.f - 512.f * v0.z, 32768.f - 512.f * v0.w};
        float4 n1 = {32768.f - 512.f * v1.x, 32768.f - 512.f * v1.y,
                     32768.f - 512.f * v1.z, 32768.f - 512.f * v1.w};
        *(float4*)&u.s.ncn[t * 4]         = n0;
        *(float4*)&u.s.ncn[(t + 512) * 4] = n1;
    }
    __syncthreads();

    unsigned int tsA[8], tsB[8];      // per-lane lists: even passes / odd passes
    #pragma unroll
    for (int i = 0; i < 8; ++i) { tsA[i] = 0u; tsB[i] = 0u; }

    const unsigned char* pb = u.s.xs8 + lane * 16;

    for (int pp = 0; pp < NPASS; ++pp) {
        const int p  = (pp + 2 * w) & 15;            // stagger waves across passes
        const int ga = p * 8 + w;                    // centroid 32-group 0..127
        f32x16 acc;
        #pragma unroll
        for (int g = 0; g < 4; ++g) {                // acc init (LDS bcast)
            float4 n0 = *(const float4*)&u.s.ncn[ga * 32 + g * 8 + 4 * half];
            acc[g*4+0]=n0.x; acc[g*4+1]=n0.y; acc[g*4+2]=n0.z; acc[g*4+3]=n0.w;
        }
        const char* ab = cb8l + (size_t)ga * 16384;
        #pragma unroll
        for (int s = 0; s < 8; ++s) {                // A from global (L2), B from LDS
            i32x4 al = *(const i32x4*)(ab + s * 2048);
            i32x4 ah = *(const i32x4*)(ab + s * 2048 + 1024);
            i32x4 bl = *(const i32x4*)(pb + s * 2048);
            i32x4 bh = *(const i32x4*)(pb + s * 2048 + 1024);
            acc = mfma_step(al, ah, bl, bh, acc);
        }
        // biased keys: scores ~[27e3,38e3] > 0 => uint-ordered; low 12 bits = 4095-idx
        const unsigned int K0 = 4095u - (unsigned int)(ga * 32) - 4u * (unsigned int)half;
        if ((pp & 1) == 0) {
            #pragma unroll
            for (int r = 0; r < 16; ++r) {
                const unsigned int cr = (unsigned int)((r & 3) + 8 * (r >> 2));
                inskey((__float_as_uint(acc[r]) & 0xFFFFF000u) | (K0 - cr), tsA);
            }
        } else {
            #pragma unroll
            for (int r = 0; r < 16; ++r) {
                const unsigned int cr = (unsigned int)((r & 3) + 8 * (r >> 2));
                inskey((__float_as_uint(acc[r]) & 0xFFFFF000u) | (K0 - cr), tsB);
            }
        }
    }

    // ---- merge ----
    __syncthreads();   // xs8 + ncn dead -> keys
    {
        const int L0 = w * 4 + half * 2;             // lists L0 (even), L0+1 (odd)
        #pragma unroll
        for (int e = 0; e < 8; ++e) {
            u.keys[(L0 * 8 + e) * 32 + m32]       = tsA[e];
            u.keys[((L0 + 1) * 8 + e) * 32 + m32] = tsB[e];
        }
    }
    __syncthreads();
    if (t < 128) {     // stage 1: 4 threads/token, 64 keys (8 lists) -> top-16 partials
        const int token = t >> 2, sub = t & 3;
        unsigned int bs[16];
        #pragma unroll
        for (int i = 0; i < 16; ++i) bs[i] = 0u;
        #pragma unroll 2
        for (int k = 0; k < 64; ++k) inskey(u.keys[(sub * 64 + k) * 32 + token], bs);
        #pragma unroll
        for (int e = 0; e < 16; ++e) pk[token * 65 + sub * 16 + e] = bs[e];
    }
    __syncthreads();
    if (t < TOKB) {    // stage 2: top-16 fp8 candidates -> global tki
        unsigned int bs[NSEL];
        #pragma unroll
        for (int i = 0; i < NSEL; ++i) bs[i] = 0u;
        #pragma unroll 2
        for (int k = 0; k < 64; ++k) inskey(pk[t * 65 + k], bs);
        #pragma unroll
        for (int r = 0; r < NSEL; ++r)
            tki_g[(size_t)blockIdx.x * (TOKB * NSEL) + t * NSEL + r] =
                4095 - (int)(bs[r] & 0xFFFu);
    }
}

// Kernel B: fp16-codebook rescore (fp32 accum) of the 16 candidates, top-8, softmax,
// fp16 decode, loss. cbh (4 MB) is the ONLY gathered table -> L2-resident.
// 256 threads / 16 tokens -> 1024 blocks for gather-latency hiding.
__global__ __launch_bounds__(256) void vq_epi(
    const float* __restrict__ x, const _Float16* __restrict__ cbh,
    const float* __restrict__ cnorm, const int* __restrict__ tki_g,
    float* __restrict__ out, float* __restrict__ loss_acc,
    unsigned int* __restrict__ ticket)
{
    __shared__ int   tkl[TOKE * NSEL];               // 256 ints
    __shared__ float tks[TOKE * 17];
    __shared__ float tkw[TOKE * TOPK];
    __shared__ int   tkif[TOKE * TOPK];
    __shared__ float redbuf[4];

    const int t    = threadIdx.x;
    const int lane = t & 63;
    const int w    = t >> 6;
    const int tok0 = blockIdx.x * TOKE;

    tkl[t] = tki_g[(size_t)blockIdx.x * (TOKE * NSEL) + t];   // 256 = 16*16 exactly
    __syncthreads();

    {   // fp16 rescore of 16 candidates: 16 threads/token, x row read ONCE,
        // thread sl owns 8-dim granules {sl+16i, i<4}: 256 B contiguous per row/quarter
        const int token = t >> 4, sl = t & 15;
        const f32x4* xr = (const f32x4*)(x + (size_t)(tok0 + token) * D_DIM);
        f32x4 xv[8];
        #pragma unroll
        for (int i = 0; i < 4; ++i) {
            xv[2*i]   = xr[(sl + 16*i) * 2];
            xv[2*i+1] = xr[(sl + 16*i) * 2 + 1];
        }
        #pragma unroll
        for (int hh = 0; hh < 2; ++hh) {
            float pd[8];
            #pragma unroll
            for (int e = 0; e < 8; ++e) {
                const int idx = tkl[token * NSEL + hh * 8 + e];
                const f16x8* cr = (const f16x8*)(cbh + (size_t)idx * D_DIM);
                float dot = 0.f;
                #pragma unroll
                for (int i = 0; i < 4; ++i) {
                    f16x8 cv = cr[sl + 16*i];
                    dot += xv[2*i].x   * (float)cv[0] + xv[2*i].y   * (float)cv[1]
                         + xv[2*i].z   * (float)cv[2] + xv[2*i].w   * (float)cv[3]
                         + xv[2*i+1].x * (float)cv[4] + xv[2*i+1].y * (float)cv[5]
                         + xv[2*i+1].z * (float)cv[6] + xv[2*i+1].w * (float)cv[7];
                }
                pd[e] = dot;
            }
            #pragma unroll
            for (int e = 0; e < 8; ++e) {
                pd[e] += __shfl_down(pd[e], 8, 16);
                pd[e] += __shfl_down(pd[e], 4, 16);
                pd[e] += __shfl_down(pd[e], 2, 16);
                pd[e] += __shfl_down(pd[e], 1, 16);
            }
            if (sl == 0) {
                #pragma unroll
                for (int e = 0; e < 8; ++e)
                    tks[token * 17 + hh * 8 + e] =
                        2.f * pd[e] - cnorm[tkl[token * NSEL + hh * 8 + e]];
            }
        }
    }
    __syncthreads();
    if (t < TOKE) {    // top-8 of the 16, softmax
        unsigned int bs[8];
        #pragma unroll
        for (int i = 0; i < 8; ++i) bs[i] = 0u;
        #pragma unroll
        for (int e = 0; e < NSEL; ++e) {
            unsigned int uu = __float_as_uint(tks[t * 17 + e]);
            uu ^= (unsigned int)((int)uu >> 31) | 0x80000000u;   // monotone float->uint
            inskey((uu & 0xFFFFFFF0u) | (unsigned int)e, bs);
        }
        const float m = tks[t * 17 + (int)(bs[0] & 15u)];
        float wv[TOPK], sum = 0.f;
        int ids[TOPK];
        #pragma unroll
        for (int r = 0; r < TOPK; ++r) {
            const int e = (int)(bs[r] & 15u);
            wv[r] = __expf(tks[t * 17 + e] - m); sum += wv[r];
            ids[r] = tkl[t * NSEL + e];
        }
        const float inv = 1.f / sum;
        #pragma unroll
        for (int r = 0; r < TOPK; ++r) {
            tkw[t * TOPK + r] = wv[r] * inv;
            tkif[t * TOPK + r] = ids[r];
        }
    }
    __syncthreads();
    // output + loss partial: fp16 decode, dense 16 B/lane float4 stores (r10 pattern)
    float lsum = 0.f;
    #pragma unroll 1
    for (int it = 0; it < (TOKE * (D_DIM / 4)) / 256; ++it) {    // 8 iters
        const int p = it * 256 + t;
        const int token = p >> 7, d4 = p & 127;
        float4 q = {0.f, 0.f, 0.f, 0.f};
        #pragma unroll
        for (int e = 0; e < TOPK; ++e) {
            const float wv = tkw[token * TOPK + e];
            const int  idx = tkif[token * TOPK + e];
            f16x4 cv = *(const f16x4*)(cbh + (size_t)idx * D_DIM + d4 * 4);
            q.x += wv * (float)cv[0]; q.y += wv * (float)cv[1];
            q.z += wv * (float)cv[2]; q.w += wv * (float)cv[3];
        }
        const size_t go = (size_t)(tok0 + token) * (D_DIM / 4) + d4;
        f32x4 xv = __builtin_nontemporal_load((const f32x4*)x + go);
        const float ex = q.x - xv.x, ey = q.y - xv.y, ez = q.z - xv.z, ew = q.w - xv.w;
        lsum += ex*ex + ey*ey + ez*ez + ew*ew;
        f32x4 qv = {q.x, q.y, q.z, q.w};
        __builtin_nontemporal_store(qv, (f32x4*)out + go);
    }
    #pragma unroll
    for (int off = 32; off > 0; off >>= 1) lsum += __shfl_down(lsum, off, 64);
    if (lane == 0) redbuf[w] = lsum;
    __syncthreads();
    if (t == 0) {
        float s = 0.f;
        #pragma unroll
        for (int i = 0; i < 4; ++i) s += redbuf[i];
        atomicAdd(loss_acc, s);
        __threadfence();
        unsigned int prev = atomicAdd(ticket, 1u);
        if (prev == (unsigned int)(gridDim.x - 1)) {   // last block finalizes loss
            __threadfence();
            float total = atomicAdd(loss_acc, 0.f);    // coherent read
            out[(size_t)N_TOK * D_DIM] = 1.25f * total / (float)((size_t)N_TOK * D_DIM);
        }
    }
}

extern "C" void kernel_launch(void* const* d_in, const int* in_sizes, int n_in,
                              void* d_out, int out_size, void* d_ws, size_t ws_size,
                              hipStream_t stream) {
    const float* x  = (const float*)d_in[0];   // [8,2048,512] fp32
    const float* cb = (const float*)d_in[1];   // [4096,512] fp32
    float* out = (float*)d_out;

    char* ws = (char*)d_ws;
    unsigned char* cbf8   = (unsigned char*)ws;              // 2 MB, fp8 fragment-ordered
    _Float16*      cbh    = (_Float16*)(ws + 2097152);       // 4 MB, fp16 row-major
    float*         cnorm  = (float*)(ws + 6291456);          // 16 KB
    float*         loss   = (float*)(ws + 6307840);          // 4 B
    unsigned int*  ticket = (unsigned int*)(ws + 6307904);   // 4 B
    int*           tki_g  = (int*)(ws + 6308096);            // 1 MB top-16 indices

    conv_cb_kernel<<<256, 256, 0, stream>>>(cb, cbf8, cbh, cnorm, loss, ticket);
    vq_main<<<N_TOK / TOKB, 512, 0, stream>>>(x, cbf8, cnorm, tki_g);
    vq_epi<<<N_TOK / TOKE, 256, 0, stream>>>(x, cbh, cnorm, tki_g, out, loss, ticket);
}